// Round 9
// baseline (272.811 us; speedup 1.0000x reference)
//
#include <hip/hip_runtime.h>

constexpr int NNODES = 50000;
constexpr int NEDGES = 800000;
constexpr int CAP = 64;   // bucket capacity; deg ~ Poisson(16), P(deg>=64) ~ 1e-19

typedef __attribute__((ext_vector_type(8))) short short8;    // 8 bf16 (4 VGPRs)
typedef __attribute__((ext_vector_type(8))) unsigned short ushort8;
typedef __attribute__((ext_vector_type(4))) float f32x4;

__device__ __forceinline__ unsigned short f2b(float f) {   // fp32 -> bf16 RTN-even
    unsigned int u = __float_as_uint(f);
    u += 0x7FFFu + ((u >> 16) & 1u);
    return (unsigned short)(u >> 16);
}
__device__ __forceinline__ float b2f(unsigned short u) {   // exact
    return __uint_as_float(((unsigned int)u) << 16);
}

// ---------------------------------------------------------------------------
// Pack W[K][N] (fp32) -> MFMA B-fragment order (bf16).
// ---------------------------------------------------------------------------
template <int N, int K>
__device__ __forceinline__ void pack_one(int idx, const float* __restrict__ W,
                                         unsigned short* __restrict__ Wp) {
    constexpr int KS = K / 32;
    int j = idx & 7;
    int lane = (idx >> 3) & 63;
    int t = idx >> 9;
    int nt = t / KS, ks = t % KS;
    int n = nt * 16 + (lane & 15);
    int k = ks * 32 + (lane >> 4) * 8 + j;
    Wp[idx] = f2b(W[(size_t)k * N + n]);
}

// prep: zero cursor (idx < NNODES) + pack all 4 weights (idx >= NNODES)
__global__ __launch_bounds__(256) void prep_kernel(int* __restrict__ cursor,
                                                   const float* __restrict__ W1,
                                                   const float* __restrict__ W2,
                                                   const float* __restrict__ W3,
                                                   const float* __restrict__ W4,
                                                   unsigned short* __restrict__ Wp1,
                                                   unsigned short* __restrict__ Wp2,
                                                   unsigned short* __restrict__ Wp3,
                                                   unsigned short* __restrict__ Wp4) {
    int idx = blockIdx.x * 256 + threadIdx.x;
    if (idx < NNODES) { cursor[idx] = 0; return; }
    int p = idx - NNODES;
    if (p < 16384) pack_one<128, 128>(p, W1, Wp1);
    else if (p < 32768) pack_one<128, 128>(p - 16384, W2, Wp2);
    else if (p < 40960) pack_one<64, 128>(p - 32768, W3, Wp3);
    else if (p < 43008) pack_one<32, 64>(p - 40960, W4, Wp4);
}

// ---------------------------------------------------------------------------
// XCD-partitioned bucket fill, LDS-compacted (scan phase -> dense drain).
// ---------------------------------------------------------------------------
constexpr int NPART = 8;
constexpr int PSIZE = NNODES / NPART;   // 6250
constexpr int FCH = 1024;               // edges scanned per block (4/thread)
constexpr int QCAP = 320;               // matches: mean 128, sd ~10.6

__global__ __launch_bounds__(256) void fill_kernel(const int* __restrict__ src,
                                                   const int* __restrict__ dst,
                                                   const float* __restrict__ val,
                                                   int* __restrict__ cursor,
                                                   int2* __restrict__ buckets) {
    __shared__ int q_e[QCAP];
    __shared__ int q_d[QCAP];
    __shared__ int qcount;
    if (threadIdx.x == 0) qcount = 0;
    __syncthreads();

    int part = blockIdx.x % NPART;
    int chunk = blockIdx.x / NPART;
    int lo = part * PSIZE, hi = lo + PSIZE;
    int e0 = chunk * FCH + threadIdx.x * 4;

    int4 d4 = make_int4(-1, -1, -1, -1);
    if (e0 + 3 < NEDGES) {
        d4 = *reinterpret_cast<const int4*>(dst + e0);
    } else if (e0 < NEDGES) {
        d4.x = dst[e0];
        if (e0 + 1 < NEDGES) d4.y = dst[e0 + 1];
        if (e0 + 2 < NEDGES) d4.z = dst[e0 + 2];
    }
    int dd[4] = {d4.x, d4.y, d4.z, d4.w};
#pragma unroll
    for (int i = 0; i < 4; ++i) {
        int d = dd[i];
        if (d >= lo && d < hi) {
            int pos = atomicAdd(&qcount, 1);
            if (pos < QCAP) {
                q_e[pos] = e0 + i;
                q_d[pos] = d;
            } else {  // overflow fallback (statistically unreachable; correct anyway)
                int e = e0 + i;
                int p = atomicAdd(&cursor[d], 1);
                if (p < CAP)
                    buckets[(size_t)d * CAP + p] = make_int2(src[e], __float_as_int(val[e]));
            }
        }
    }
    __syncthreads();

    int n = qcount < QCAP ? qcount : QCAP;
    for (int i = threadIdx.x; i < n; i += 256) {
        int e = q_e[i];
        int d = q_d[i];
        int s = src[e];
        float v = val[e];
        int p = atomicAdd(&cursor[d], 1);
        if (p < CAP)
            buckets[(size_t)d * CAP + p] = make_int2(s, __float_as_int(v));
    }
}

// ---------------------------------------------------------------------------
// MFMA bf16 GEMM: Sb = H @ W. Block = 4 waves x 16 rows = 64 rows, full N.
// ---------------------------------------------------------------------------
template <int N, int K, bool AF32>
__global__ __launch_bounds__(256) void mfma_gemm_kernel(const void* __restrict__ Hv,
                                                        const unsigned short* __restrict__ Wp,
                                                        unsigned short* __restrict__ Sb) {
    constexpr int NT = N / 16, KS = K / 32;
    const int lane = threadIdx.x & 63;
    const int wave = threadIdx.x >> 6;
    const int waveRow = blockIdx.x * 64 + wave * 16;
    const int m = lane & 15, quad = lane >> 4;
    int arow = waveRow + m;
    if (arow >= NNODES) arow = NNODES - 1;      // clamp; stores are guarded

    f32x4 acc[NT];
#pragma unroll
    for (int nt = 0; nt < NT; ++nt) acc[nt] = (f32x4){0.f, 0.f, 0.f, 0.f};

#pragma unroll
    for (int ks = 0; ks < KS; ++ks) {
        short8 a;
        if (AF32) {
            const float* hp = (const float*)Hv + (size_t)arow * K + ks * 32 + quad * 8;
            float4 a0 = *reinterpret_cast<const float4*>(hp);
            float4 a1 = *reinterpret_cast<const float4*>(hp + 4);
            a[0] = (short)f2b(a0.x); a[1] = (short)f2b(a0.y);
            a[2] = (short)f2b(a0.z); a[3] = (short)f2b(a0.w);
            a[4] = (short)f2b(a1.x); a[5] = (short)f2b(a1.y);
            a[6] = (short)f2b(a1.z); a[7] = (short)f2b(a1.w);
        } else {
            a = *reinterpret_cast<const short8*>(
                (const unsigned short*)Hv + (size_t)arow * K + ks * 32 + quad * 8);
        }
#pragma unroll
        for (int nt = 0; nt < NT; ++nt) {
            short8 b = *reinterpret_cast<const short8*>(Wp + ((nt * KS + ks) * 64 + lane) * 8);
            acc[nt] = __builtin_amdgcn_mfma_f32_16x16x32_bf16(a, b, acc[nt], 0, 0, 0);
        }
    }

#pragma unroll
    for (int reg = 0; reg < 4; ++reg) {
        int grow = waveRow + quad * 4 + reg;
        if (grow < NNODES) {
#pragma unroll
            for (int nt = 0; nt < NT; ++nt)
                Sb[(size_t)grow * N + nt * 16 + m] = f2b(acc[nt][reg]);
        }
    }
}

// ---------------------------------------------------------------------------
// Pull aggregation, software-pipelined: while FMAs consume edge-group k's
// rows, group k+1's edge records AND row-gathers are already in flight
// (~8 outstanding 16B gathers/thread). fp32 accumulate.
// ---------------------------------------------------------------------------
template <int N, bool BOUT>
__global__ __launch_bounds__(256) void agg_kernel(const unsigned short* __restrict__ Sb,
                                                  const int2* __restrict__ buckets,
                                                  const int* __restrict__ counts,
                                                  const float* __restrict__ bias,
                                                  void* __restrict__ outp) {
    constexpr int NCH = N / 8;
    constexpr int NPB = 256 / NCH;
    int node = blockIdx.x * NPB + threadIdx.x / NCH;
    int cg = threadIdx.x % NCH;
    if (node >= NNODES) return;
    int cnt = counts[node];
    if (cnt > CAP) cnt = CAP;
    const int2* eb = buckets + (size_t)node * CAP;
    const unsigned short* tab = Sb + cg * 8;
    float acc[8];
#pragma unroll
    for (int t = 0; t < 8; ++t) acc[t] = bias[cg * 8 + t];

    int j = 0;
    int4 ca, cc;
    ushort8 r0, r1, r2, r3;
    if (j + 4 <= cnt) {
        ca = *reinterpret_cast<const int4*>(eb);
        cc = *reinterpret_cast<const int4*>(eb + 2);
        r0 = *reinterpret_cast<const ushort8*>(tab + (size_t)ca.x * N);
        r1 = *reinterpret_cast<const ushort8*>(tab + (size_t)ca.z * N);
        r2 = *reinterpret_cast<const ushort8*>(tab + (size_t)cc.x * N);
        r3 = *reinterpret_cast<const ushort8*>(tab + (size_t)cc.z * N);
    }
    while (j + 4 <= cnt) {
        int nj = j + 4;
        bool more = (nj + 4 <= cnt);
        int4 na, nc;
        ushort8 s0, s1, s2, s3;
        if (more) {   // next group's edge records + gathers issued BEFORE fma
            na = *reinterpret_cast<const int4*>(eb + nj);
            nc = *reinterpret_cast<const int4*>(eb + nj + 2);
            s0 = *reinterpret_cast<const ushort8*>(tab + (size_t)na.x * N);
            s1 = *reinterpret_cast<const ushort8*>(tab + (size_t)na.z * N);
            s2 = *reinterpret_cast<const ushort8*>(tab + (size_t)nc.x * N);
            s3 = *reinterpret_cast<const ushort8*>(tab + (size_t)nc.z * N);
        }
        float v0 = __int_as_float(ca.y), v1 = __int_as_float(ca.w);
        float v2 = __int_as_float(cc.y), v3 = __int_as_float(cc.w);
#pragma unroll
        for (int t = 0; t < 8; ++t) {
            acc[t] = fmaf(b2f(r0[t]), v0, acc[t]);
            acc[t] = fmaf(b2f(r1[t]), v1, acc[t]);
            acc[t] = fmaf(b2f(r2[t]), v2, acc[t]);
            acc[t] = fmaf(b2f(r3[t]), v3, acc[t]);
        }
        if (more) {
            ca = na; cc = nc;
            r0 = s0; r1 = s1; r2 = s2; r3 = s3;
        }
        j = nj;
    }
    for (; j < cnt; ++j) {
        int2 e = eb[j];
        float v = __int_as_float(e.y);
        const ushort8 mr = *reinterpret_cast<const ushort8*>(tab + (size_t)e.x * N);
#pragma unroll
        for (int t = 0; t < 8; ++t) acc[t] = fmaf(b2f(mr[t]), v, acc[t]);
    }

    if (BOUT) {
        ushort8 o;
#pragma unroll
        for (int t = 0; t < 8; ++t) o[t] = f2b(fmaxf(acc[t], 0.f));
        *reinterpret_cast<ushort8*>((unsigned short*)outp + (size_t)node * N + cg * 8) = o;
    } else {
        float* op = (float*)outp + (size_t)node * N + cg * 8;
        *reinterpret_cast<float4*>(op) = make_float4(acc[0], acc[1], acc[2], acc[3]);
        *reinterpret_cast<float4*>(op + 4) = make_float4(acc[4], acc[5], acc[6], acc[7]);
    }
}

extern "C" void kernel_launch(void* const* d_in, const int* in_sizes, int n_in,
                              void* d_out, int out_size, void* d_ws, size_t ws_size,
                              hipStream_t stream) {
    const float* x   = (const float*)d_in[0];
    const int*   src = (const int*)d_in[1];
    const int*   dst = (const int*)d_in[2];
    const float* val = (const float*)d_in[3];
    const float* W1  = (const float*)d_in[4];
    const float* b1  = (const float*)d_in[5];
    const float* W2  = (const float*)d_in[6];
    const float* b2  = (const float*)d_in[7];
    const float* W3  = (const float*)d_in[8];
    const float* b3  = (const float*)d_in[9];
    const float* W4  = (const float*)d_in[10];
    const float* b4  = (const float*)d_in[11];
    float* out = (float*)d_out;

    unsigned short* P = (unsigned short*)d_ws;            // bf16 50000x128
    unsigned short* Q = P + (size_t)NNODES * 128;         // bf16 50000x128
    int2* buckets = (int2*)(Q + (size_t)NNODES * 128);    // NNODES*CAP int2 = 25.6 MB
    unsigned short* Wp1 = (unsigned short*)(buckets + (size_t)NNODES * CAP);
    unsigned short* Wp2 = Wp1 + 128 * 128;
    unsigned short* Wp3 = Wp2 + 128 * 128;
    unsigned short* Wp4 = Wp3 + 128 * 64;
    int* cursor = (int*)(Wp4 + 64 * 32);                  // NNODES (counter, then degree)

    const dim3 blk(256);
    const int gemmGrid = (NNODES + 63) / 64;              // 782
    const int prepGrid = (NNODES + 43008 + 255) / 256;
    const int fillGrid = ((NEDGES + FCH - 1) / FCH) * NPART;

    prep_kernel<<<prepGrid, blk, 0, stream>>>(cursor, W1, W2, W3, W4, Wp1, Wp2, Wp3, Wp4);
    fill_kernel<<<fillGrid, blk, 0, stream>>>(src, dst, val, cursor, buckets);

    mfma_gemm_kernel<128, 128, true><<<gemmGrid, blk, 0, stream>>>(x, Wp1, Q);
    agg_kernel<128, true><<<(NNODES + 15) / 16, blk, 0, stream>>>(Q, buckets, cursor, b1, P);
    mfma_gemm_kernel<128, 128, false><<<gemmGrid, blk, 0, stream>>>(P, Wp2, Q);
    agg_kernel<128, true><<<(NNODES + 15) / 16, blk, 0, stream>>>(Q, buckets, cursor, b2, P);
    mfma_gemm_kernel<64, 128, false><<<gemmGrid, blk, 0, stream>>>(P, Wp3, Q);
    agg_kernel<64, true><<<(NNODES + 31) / 32, blk, 0, stream>>>(Q, buckets, cursor, b3, P);
    mfma_gemm_kernel<32, 64, false><<<gemmGrid, blk, 0, stream>>>(P, Wp4, Q);
    agg_kernel<32, false><<<(NNODES + 63) / 64, blk, 0, stream>>>(Q, buckets, cursor, b4, out);
}